// Round 3
// baseline (755.357 us; speedup 1.0000x reference)
//
#include <hip/hip_runtime.h>

#define VOCAB 32000
#define EMB   512
#define ENC2  1024
#define DECH  1024
#define ATTN  512
#define BB    64
#define SS    128
#define KXH   2560
#define KOI   2560   // [nh 1024 | ctx 1024 | emb 512]

typedef __attribute__((ext_vector_type(4))) float  f32x4;
typedef __attribute__((ext_vector_type(8))) __bf16 bf16x8;

// ws layout (bytes)
#define OFF_SC   0          // scores   64x128 f32        (32768)
#define OFF_CTXP 32768      // ctx partials 4x64x1024 f32 (1048576)
#define OFF_GP   1081344    // gate part 4x64x4096 f32    (4194304)
#define OFF_XE   5275648    // emb bf16 64x512            (65536)
#define OFF_OI   5341184    // out_in bf16 64x2560        (327680)
#define OFF_WE   5668864    // W_enc bf16 512x1024        (1048576)
#define OFF_DP   6717440    // dec_proj 64x512 f32        (131072)

static __device__ __forceinline__ bf16x8 cvt8(const float* p) {
    f32x4 a = *(const f32x4*)p;
    f32x4 b = *(const f32x4*)(p + 4);
    bf16x8 t;
    t[0] = (__bf16)a[0]; t[1] = (__bf16)a[1]; t[2] = (__bf16)a[2]; t[3] = (__bf16)a[3];
    t[4] = (__bf16)b[0]; t[5] = (__bf16)b[1]; t[6] = (__bf16)b[2]; t[7] = (__bf16)b[3];
    return t;
}

// sum of 4 context partials (stride 64*1024 f32) then cvt to bf16x8
static __device__ __forceinline__ bf16x8 sum4cvt(const float* p) {
    f32x4 a = *(const f32x4*)p;
    f32x4 b = *(const f32x4*)(p + 4);
    a += *(const f32x4*)(p + 65536);  b += *(const f32x4*)(p + 65536 + 4);
    a += *(const f32x4*)(p + 131072); b += *(const f32x4*)(p + 131072 + 4);
    a += *(const f32x4*)(p + 196608); b += *(const f32x4*)(p + 196608 + 4);
    bf16x8 t;
    t[0] = (__bf16)a[0]; t[1] = (__bf16)a[1]; t[2] = (__bf16)a[2]; t[3] = (__bf16)a[3];
    t[4] = (__bf16)b[0]; t[5] = (__bf16)b[1]; t[6] = (__bf16)b[2]; t[7] = (__bf16)b[3];
    return t;
}

static __device__ __forceinline__ f32x4 mfma16(bf16x8 a, bf16x8 b, f32x4 c) {
    return __builtin_amdgcn_mfma_f32_16x16x32_bf16(a, b, c, 0, 0, 0);
}

// ---- fused init: [0,256) cvt_we | [256,320) emb gather | [320,328) decproj
__global__ __launch_bounds__(256) void k_init(const float* __restrict__ We,
                                              __bf16* __restrict__ we16,
                                              const int* __restrict__ tok,
                                              const float* __restrict__ hidden,
                                              const float* __restrict__ emb,
                                              __bf16* __restrict__ xe,
                                              __bf16* __restrict__ oi,
                                              const float* __restrict__ Wd,
                                              float* __restrict__ dp) {
    int bid = blockIdx.x, t = threadIdx.x;
    if (bid < 256) {
        int base = (bid * 256 + t) * 8;
        *(bf16x8*)(we16 + base) = cvt8(We + base);
    } else if (bid < 320) {
        int b = bid - 256;
        int tk = tok[b];
        #pragma unroll
        for (int j = 0; j < 2; ++j) {
            int e = t + 256 * j;
            float v = (tk == 0) ? 0.f : emb[tk * EMB + e];
            __bf16 h = (__bf16)v;
            xe[b * EMB + e] = h;
            oi[b * KOI + 2048 + e] = h;
        }
    } else {
        // dec_proj = hidden @ W_dec^T via MFMA  [64,512]
        int bx = bid - 320;
        int w = t >> 6, l = t & 63, lo = l & 15, hi = l >> 4;
        int n = bx * 64 + w * 16 + lo;
        f32x4 acc[4];
        #pragma unroll
        for (int m = 0; m < 4; ++m) acc[m] = (f32x4){0.f, 0.f, 0.f, 0.f};
        for (int k0 = 0; k0 < DECH; k0 += 32) {
            int k = k0 + hi * 8;
            bf16x8 bf = cvt8(Wd + n * DECH + k);
            #pragma unroll
            for (int m = 0; m < 4; ++m) {
                bf16x8 af = cvt8(hidden + (m * 16 + lo) * DECH + k);
                acc[m] = mfma16(af, bf, acc[m]);
            }
        }
        #pragma unroll
        for (int m = 0; m < 4; ++m)
            #pragma unroll
            for (int ri = 0; ri < 4; ++ri) {
                int b = m * 16 + hi * 4 + ri;
                dp[b * ATTN + n] = acc[m][ri];
            }
    }
}

// ---- fused scores: tanh(enc@We^T + dp) . v  -> sc[b][s] (plain store) --
// 256 blocks x 32 rows (s fixed per block); 4 waves cover 4x128 cols
__global__ __launch_bounds__(256) void k_scores(const float* __restrict__ enc,
                                                const __bf16* __restrict__ we16,
                                                const float* __restrict__ dp,
                                                const float* __restrict__ v,
                                                float* __restrict__ sc) {
    int t = threadIdx.x;
    int w = t >> 6, l = t & 63, lo = l & 15, hi = l >> 4;
    int r0 = blockIdx.x * 32;
    int cb = w * 128;
    __shared__ float lds_p[4][32];
    f32x4 acc[2][8];
    #pragma unroll
    for (int m = 0; m < 2; ++m)
        #pragma unroll
        for (int f = 0; f < 8; ++f) acc[m][f] = (f32x4){0.f, 0.f, 0.f, 0.f};

    const float* arow0 = enc + (r0 + lo) * ENC2 + hi * 8;
    const float* arow1 = enc + (r0 + 16 + lo) * ENC2 + hi * 8;
    for (int k0 = 0; k0 < ENC2; k0 += 32) {
        bf16x8 a0 = cvt8(arow0 + k0);
        bf16x8 a1 = cvt8(arow1 + k0);
        #pragma unroll
        for (int f = 0; f < 8; ++f) {
            bf16x8 bf = *(const bf16x8*)(we16 + (cb + f * 16 + lo) * ENC2 + k0 + hi * 8);
            acc[0][f] = mfma16(a0, bf, acc[0][f]);
            acc[1][f] = mfma16(a1, bf, acc[1][f]);
        }
    }
    float p[2][4] = {{0.f,0.f,0.f,0.f},{0.f,0.f,0.f,0.f}};
    #pragma unroll
    for (int f = 0; f < 8; ++f) {
        int c = cb + f * 16 + lo;
        float vv = v[c];
        #pragma unroll
        for (int m = 0; m < 2; ++m)
            #pragma unroll
            for (int ri = 0; ri < 4; ++ri) {
                int b = (r0 + m * 16 + hi * 4 + ri) & 63;
                p[m][ri] += vv * tanhf(acc[m][f][ri] + dp[b * ATTN + c]);
            }
    }
    #pragma unroll
    for (int x = 1; x < 16; x <<= 1) {
        #pragma unroll
        for (int m = 0; m < 2; ++m)
            #pragma unroll
            for (int ri = 0; ri < 4; ++ri) p[m][ri] += __shfl_xor(p[m][ri], x);
    }
    if (lo == 0) {
        #pragma unroll
        for (int m = 0; m < 2; ++m)
            #pragma unroll
            for (int ri = 0; ri < 4; ++ri) lds_p[w][m * 16 + hi * 4 + ri] = p[m][ri];
    }
    __syncthreads();
    if (t < 32) {
        float s_ = lds_p[0][t] + lds_p[1][t] + lds_p[2][t] + lds_p[3][t];
        int r = r0 + t;
        sc[(r & 63) * SS + (r >> 6)] = s_;
    }
}

// ---- fused softmax + context partial: 256 blocks = (b, s-chunk of 32) --
__global__ __launch_bounds__(256) void k_ctx(const float* __restrict__ enc,
                                             const float* __restrict__ sc,
                                             const int* __restrict__ mask,
                                             float* __restrict__ ctxp,
                                             float* __restrict__ attn) {
    int b = blockIdx.x & 63, sl = blockIdx.x >> 6, t = threadIdx.x;
    __shared__ float ws_[SS];
    __shared__ float red[4];
    float val = 0.f, e = 0.f;
    if (t < SS) {
        val = sc[b * SS + t];
        if (mask[b * SS + t] == 0) val = -3.0e38f;
        float m = val;
        #pragma unroll
        for (int x = 32; x >= 1; x >>= 1) m = fmaxf(m, __shfl_xor(m, x));
        if ((t & 63) == 0) red[t >> 6] = m;
    }
    __syncthreads();
    float M = fmaxf(red[0], red[1]);
    if (t < SS) {
        e = expf(val - M);
        float s = e;
        #pragma unroll
        for (int x = 32; x >= 1; x >>= 1) s += __shfl_xor(s, x);
        if ((t & 63) == 0) red[2 + (t >> 6)] = s;
    }
    __syncthreads();
    float inv = 1.f / (red[2] + red[3]);
    if (t < SS) {
        float wv = e * inv;
        ws_[t] = wv;
        if (sl == 0) attn[b * SS + t] = wv;
    }
    __syncthreads();

    float acc[4] = {0.f, 0.f, 0.f, 0.f};
    for (int si = 0; si < 32; ++si) {
        int s = sl * 32 + si;
        float wv = ws_[s];
        const float* ep = enc + (s * BB + b) * ENC2;
        #pragma unroll
        for (int j = 0; j < 4; ++j) acc[j] += wv * ep[t + 256 * j];
    }
    float* outp = ctxp + (sl * 64 + b) * ENC2;
    #pragma unroll
    for (int j = 0; j < 4; ++j) outp[t + 256 * j] = acc[j];
}

// ---- gates GEMM: [64,4096] = x @ [W_ih|W_hh]^T, split-K=4 --------------
// A piecewise: k<512 emb bf16 | 512..1536 ctx partial-sum cvt | >=1536 hidden cvt
__global__ __launch_bounds__(256) void k_gates(const __bf16* __restrict__ xe,
                                               const float* __restrict__ ctxp,
                                               const float* __restrict__ hidden,
                                               const float* __restrict__ Wih,
                                               const float* __restrict__ Whh,
                                               float* __restrict__ gp) {
    int bx = blockIdx.x, ks = blockIdx.y;
    int t = threadIdx.x, w = t >> 6, l = t & 63, lo = l & 15, hi = l >> 4;
    int n = bx * 64 + w * 16 + lo;
    f32x4 acc[4];
    #pragma unroll
    for (int m = 0; m < 4; ++m) acc[m] = (f32x4){0.f, 0.f, 0.f, 0.f};
    int kend = ks * 640 + 640;
    for (int k0 = ks * 640; k0 < kend; k0 += 32) {
        int k = k0 + hi * 8;
        const float* bp = (k0 < 1536) ? (Wih + n * 1536 + k) : (Whh + n * 1024 + (k - 1536));
        bf16x8 bf = cvt8(bp);
        #pragma unroll
        for (int m = 0; m < 4; ++m) {
            int row = m * 16 + lo;
            bf16x8 af;
            if (k0 < 512)        af = *(const bf16x8*)(xe + row * EMB + k);
            else if (k0 < 1536)  af = sum4cvt(ctxp + row * ENC2 + (k - 512));
            else                 af = cvt8(hidden + row * DECH + (k - 1536));
            acc[m] = mfma16(af, bf, acc[m]);
        }
    }
    float* out = gp + ks * (BB * 4096);
    #pragma unroll
    for (int m = 0; m < 4; ++m)
        #pragma unroll
        for (int ri = 0; ri < 4; ++ri) {
            int row = m * 16 + hi * 4 + ri;
            out[row * 4096 + n] = acc[m][ri];
        }
}

// ---- LSTM pointwise + ctx finalize into oi -----------------------------
__global__ void k_lstm(const float* __restrict__ gp, const float* __restrict__ bih,
                       const float* __restrict__ bhh, const float* __restrict__ cell,
                       const float* __restrict__ ctxp,
                       float* __restrict__ nh_out, float* __restrict__ nc_out,
                       __bf16* __restrict__ oi) {
    int b = blockIdx.x, t = threadIdx.x;
    #pragma unroll
    for (int j = 0; j < 4; ++j) {
        int h = t + 256 * j;
        float gi = 0.f, gf = 0.f, gg = 0.f, go = 0.f;
        #pragma unroll
        for (int ks = 0; ks < 4; ++ks) {
            const float* g = gp + ks * (BB * 4096) + b * 4096;
            gi += g[h]; gf += g[1024 + h]; gg += g[2048 + h]; go += g[3072 + h];
        }
        gi += bih[h] + bhh[h];
        gf += bih[1024 + h] + bhh[1024 + h];
        gg += bih[2048 + h] + bhh[2048 + h];
        go += bih[3072 + h] + bhh[3072 + h];
        float i_ = 1.f / (1.f + expf(-gi));
        float f_ = 1.f / (1.f + expf(-gf));
        float o_ = 1.f / (1.f + expf(-go));
        float g_ = tanhf(gg);
        float nc = f_ * cell[b * DECH + h] + i_ * g_;
        float nh = o_ * tanhf(nc);
        nc_out[b * DECH + h] = nc;
        nh_out[b * DECH + h] = nh;
        oi[b * KOI + h] = (__bf16)nh;
        // ctx finalize
        float c4 = ctxp[b * ENC2 + h] + ctxp[65536 + b * ENC2 + h]
                 + ctxp[131072 + b * ENC2 + h] + ctxp[196608 + b * ENC2 + h];
        oi[b * KOI + 1024 + h] = (__bf16)c4;
    }
}

// ---- output GEMM: [64,32000] = out_in @ W_out^T + b_out ----------------
__global__ __launch_bounds__(256) void k_out(const __bf16* __restrict__ oi,
                                             const float* __restrict__ Wo,
                                             const float* __restrict__ bo,
                                             float* __restrict__ out) {
    int bx = blockIdx.x;
    int t = threadIdx.x, w = t >> 6, l = t & 63, lo = l & 15, hi = l >> 4;
    int n = bx * 64 + w * 16 + lo;
    f32x4 acc[4];
    #pragma unroll
    for (int m = 0; m < 4; ++m) acc[m] = (f32x4){0.f, 0.f, 0.f, 0.f};
    const float* wrow = Wo + (long)n * KOI;
    for (int k0 = 0; k0 < KOI; k0 += 32) {
        int k = k0 + hi * 8;
        bf16x8 bf = cvt8(wrow + k);
        #pragma unroll
        for (int m = 0; m < 4; ++m) {
            bf16x8 af = *(const bf16x8*)(oi + (m * 16 + lo) * KOI + k);
            acc[m] = mfma16(af, bf, acc[m]);
        }
    }
    float bb = bo[n];
    #pragma unroll
    for (int m = 0; m < 4; ++m)
        #pragma unroll
        for (int ri = 0; ri < 4; ++ri) {
            int row = m * 16 + hi * 4 + ri;
            out[row * VOCAB + n] = acc[m][ri] + bb;
        }
}

extern "C" void kernel_launch(void* const* d_in, const int* in_sizes, int n_in,
                              void* d_out, int out_size, void* d_ws, size_t ws_size,
                              hipStream_t stream) {
    const int*   tok    = (const int*)d_in[0];
    const float* hidden = (const float*)d_in[1];
    const float* cell   = (const float*)d_in[2];
    const float* enc    = (const float*)d_in[3];
    const int*   mask   = (const int*)d_in[4];
    const float* emb    = (const float*)d_in[5];
    const float* We     = (const float*)d_in[6];
    const float* Wd     = (const float*)d_in[7];
    const float* v      = (const float*)d_in[8];
    const float* Wih    = (const float*)d_in[9];
    const float* Whh    = (const float*)d_in[10];
    const float* bih    = (const float*)d_in[11];
    const float* bhh    = (const float*)d_in[12];
    const float* Wo     = (const float*)d_in[13];
    const float* bo     = (const float*)d_in[14];

    char* ws = (char*)d_ws;
    float*  sc   = (float*)(ws + OFF_SC);
    float*  ctxp = (float*)(ws + OFF_CTXP);
    float*  gp   = (float*)(ws + OFF_GP);
    __bf16* xe   = (__bf16*)(ws + OFF_XE);
    __bf16* oi   = (__bf16*)(ws + OFF_OI);
    __bf16* we16 = (__bf16*)(ws + OFF_WE);
    float*  dp   = (float*)(ws + OFF_DP);

    float* out_logits = (float*)d_out;                 // [64,32000]
    float* nh   = out_logits + BB * VOCAB;             // [64,1024]
    float* nc   = nh + BB * DECH;                      // [64,1024]
    float* attn = nc + BB * DECH;                      // [64,128]

    k_init<<<328, 256, 0, stream>>>(We, we16, tok, hidden, emb, xe, oi, Wd, dp);
    k_scores<<<256, 256, 0, stream>>>(enc, we16, dp, v, sc);
    k_ctx<<<256, 256, 0, stream>>>(enc, sc, mask, ctxp, attn);
    dim3 g2(64, 4);
    k_gates<<<g2, 256, 0, stream>>>(xe, ctxp, hidden, Wih, Whh, gp);
    k_lstm<<<BB, 256, 0, stream>>>(gp, bih, bhh, cell, ctxp, nh, nc, oi);
    k_out<<<500, 256, 0, stream>>>(oi, Wo, bo, out_logits);
}